// Round 1
// baseline (266.341 us; speedup 1.0000x reference)
//
#include <hip/hip_runtime.h>
#include <hip/hip_bf16.h>
#include <stdint.h>

#define S_LEN 4096
#define D_MODEL 1024
#define N_HEADS 16
#define D_HEAD 64

typedef __attribute__((ext_vector_type(4))) float f32x4;
typedef __attribute__((ext_vector_type(8))) __bf16 bf16x8;

__device__ __forceinline__ unsigned short f2bf(float f) {
    union { float f; unsigned u; } x{f};
    unsigned r = x.u + 0x7fff + ((x.u >> 16) & 1);
    return (unsigned short)(r >> 16);
}

__device__ __forceinline__ void gld_lds16(const void* g, void* l) {
    __builtin_amdgcn_global_load_lds(
        (const __attribute__((address_space(1))) unsigned int*)g,
        (__attribute__((address_space(3))) unsigned int*)l, 16, 0, 0);
}

// ---------------- f32 -> bf16 convert ----------------
__global__ __launch_bounds__(256) void to_bf16_k(const float* __restrict__ src,
                                                 unsigned short* __restrict__ dst, int n) {
    int i = (blockIdx.x * 256 + threadIdx.x) * 4;
    if (i < n) {
        float4 v = *(const float4*)&src[i];
        ushort4 o;
        o.x = f2bf(v.x); o.y = f2bf(v.y); o.z = f2bf(v.z); o.w = f2bf(v.w);
        *(ushort4*)&dst[i] = o;
    }
}

// ---------------- RoPE cos/sin tables ----------------
__global__ __launch_bounds__(256) void rope_tables_k(const int* __restrict__ pos,
                                                     float* __restrict__ ct,
                                                     float* __restrict__ st) {
    int i = blockIdx.x * 256 + threadIdx.x;   // [0, 4096*32)
    int s = i >> 5, k = i & 31;
    // inv_freq = 10000^(-(2k)/64) = exp2(-(2k)/64 * log2(10000))
    float invf = __builtin_exp2f(-(float)(2 * k) * (1.0f / 64.0f) * 13.287712379549449f);
    float ang = (float)pos[s] * invf;
    ct[i] = cosf(ang);
    st[i] = sinf(ang);
}

// ---------------- NT GEMM: C[m,n] = sum_k A[m,k]*B[n,k] ----------------
// MODE 0: bf16 out; MODE 1: RoPE epilogue + bf16 out; MODE 2: f32 out
template <int MODE>
__global__ __launch_bounds__(256) void gemm_nt_k(const unsigned short* __restrict__ A,
                                                 const unsigned short* __restrict__ B,
                                                 void* __restrict__ Cout,
                                                 int M, int N, int K,
                                                 const float* __restrict__ costab,
                                                 const float* __restrict__ sintab) {
    __shared__ unsigned short lA[128 * 64];
    __shared__ unsigned short lB[128 * 64];
    const int t = threadIdx.x, w = t >> 6, l = t & 63;
    const int tm = blockIdx.y * 128, tn = blockIdx.x * 128;
    const int wm = (w >> 1) * 64, wn = (w & 1) * 64;
    const int g = l >> 4, ln = l & 15;

    f32x4 acc[4][4] = {};

    for (int k0 = 0; k0 < K; k0 += 64) {
        for (int r = 0; r < 4; ++r) {
            int row = 8 * (4 * r + w) + (l >> 3);
            const unsigned short* ga = A + (size_t)(tm + row) * K + k0 + (l & 7) * 8;
            gld_lds16(ga, &lA[(4 * r + w) * 512]);
            const unsigned short* gb = B + (size_t)(tn + row) * K + k0 + (l & 7) * 8;
            gld_lds16(gb, &lB[(4 * r + w) * 512]);
        }
        asm volatile("s_waitcnt vmcnt(0)" ::: "memory");
        __syncthreads();

        for (int kk = 0; kk < 2; ++kk) {
            bf16x8 af[4], bf[4];
            for (int i = 0; i < 4; ++i) {
                af[i] = *(const bf16x8*)&lA[(wm + i * 16 + ln) * 64 + kk * 32 + g * 8];
                bf[i] = *(const bf16x8*)&lB[(wn + i * 16 + ln) * 64 + kk * 32 + g * 8];
            }
            for (int i = 0; i < 4; ++i)
                for (int j = 0; j < 4; ++j)
                    acc[i][j] = __builtin_amdgcn_mfma_f32_16x16x32_bf16(af[i], bf[j], acc[i][j], 0, 0, 0);
        }
        __syncthreads();
    }

    // epilogue
    for (int i = 0; i < 4; ++i) {
        for (int j = 0; j < 4; ++j) {
            int col = tn + wn + j * 16 + ln;
            for (int r = 0; r < 4; ++r) {
                int row = tm + wm + i * 16 + g * 4 + r;
                float v = acc[i][j][r];
                if (MODE == 1) {
                    float p = __shfl_xor(v, 1, 64);
                    int dd = col & 63;
                    int kidx = dd >> 1;
                    float c = costab[row * 32 + kidx];
                    float s = sintab[row * 32 + kidx];
                    v = (dd & 1) ? (s * p + c * v) : (c * v - s * p);
                }
                if (MODE == 2)
                    ((float*)Cout)[(size_t)row * N + col] = v;
                else
                    ((unsigned short*)Cout)[(size_t)row * N + col] = f2bf(v);
            }
        }
    }
}

// ---------------- causal flash attention ----------------
// grid: (16 heads, 64 qblocks). block: 256 thr = 4 waves, wave = 16 q rows.
__global__ __launch_bounds__(256) void attn_k(const unsigned short* __restrict__ Qb,
                                              const unsigned short* __restrict__ Kb,
                                              const unsigned short* __restrict__ Vb,
                                              unsigned short* __restrict__ ctxb) {
    __shared__ unsigned short lK[64 * 64];   // K tile, row-major [k][d], XOR-swizzled
    __shared__ unsigned short lVT[64 * 64];  // V^T tile [d][k], XOR-swizzled
    __shared__ unsigned short lP[4][16 * 64]; // per-wave P tile [q][k], XOR-swizzled

    const int t = threadIdx.x, w = t >> 6, l = t & 63;
    const int h = blockIdx.x;
    const int qb = (gridDim.y - 1) - blockIdx.y;   // heavy blocks first
    const int q0 = qb * 64 + w * 16;
    const int g = l >> 4, ln = l & 15;

    // Q fragments (A-operand), resident in registers
    bf16x8 aq[2];
    for (int kk = 0; kk < 2; ++kk)
        aq[kk] = *(const bf16x8*)&Qb[(size_t)(q0 + ln) * D_MODEL + h * 64 + kk * 32 + g * 8];

    f32x4 acc[4] = {};
    float rm[4], rs[4];
    for (int r = 0; r < 4; ++r) { rm[r] = -INFINITY; rs[r] = 0.0f; }

    for (int kt = 0; kt <= qb; ++kt) {
        // ---- stage K via global_load_lds with source-side XOR pre-swizzle ----
        for (int r2 = 0; r2 < 2; ++r2) {
            int row = r2 * 32 + w * 8 + (l >> 3);
            int chunk = (l & 7) ^ (l >> 3);   // row&7 == l>>3 here
            const unsigned short* gk = Kb + (size_t)(kt * 64 + row) * D_MODEL + h * 64 + chunk * 8;
            gld_lds16(gk, &lK[r2 * 2048 + w * 512]);
        }
        // ---- stage V transposed (scalar writes), swizzled ----
        {
            int vrow = t >> 2;          // k-local
            int dch = (t & 3) * 16;     // d chunk
            const unsigned short* gv = Vb + (size_t)(kt * 64 + vrow) * D_MODEL + h * 64 + dch;
            union { uint4 v[2]; unsigned short u[16]; } tmp;
            tmp.v[0] = *(const uint4*)gv;
            tmp.v[1] = *(const uint4*)(gv + 8);
            for (int e = 0; e < 16; ++e) {
                int drow = dch + e;
                int byteoff = (drow * 128 + vrow * 2) ^ ((drow & 7) << 4);
                *(unsigned short*)((char*)lVT + byteoff) = tmp.u[e];
            }
        }
        asm volatile("s_waitcnt vmcnt(0)" ::: "memory");
        __syncthreads();

        // ---- S = Q K^T ----
        f32x4 s4[4];
        for (int ct = 0; ct < 4; ++ct) {
            f32x4 z = {};
            for (int kk = 0; kk < 2; ++kk) {
                int row = ct * 16 + ln;
                int byteoff = (row * 128 + kk * 64 + g * 16) ^ ((row & 7) << 4);
                bf16x8 bk = *(const bf16x8*)((const char*)lK + byteoff);
                z = __builtin_amdgcn_mfma_f32_16x16x32_bf16(aq[kk], bk, z, 0, 0, 0);
            }
            s4[ct] = z;
        }

        // ---- scale + causal mask + online softmax ----
        float p[4][4];
        float tilemax[4] = {-INFINITY, -INFINITY, -INFINITY, -INFINITY};
        for (int ct = 0; ct < 4; ++ct) {
            int colg = kt * 64 + ct * 16 + ln;
            for (int r = 0; r < 4; ++r) {
                int rowg = q0 + g * 4 + r;
                float v = s4[ct][r] * 0.125f;
                if (colg > rowg) v = -INFINITY;
                p[ct][r] = v;
                tilemax[r] = fmaxf(tilemax[r], v);
            }
        }
        for (int m = 1; m < 16; m <<= 1)
            for (int r = 0; r < 4; ++r)
                tilemax[r] = fmaxf(tilemax[r], __shfl_xor(tilemax[r], m, 64));
        float fac[4];
        for (int r = 0; r < 4; ++r) {
            float mn = fmaxf(rm[r], tilemax[r]);
            fac[r] = __expf(rm[r] - mn);
            rm[r] = mn;
        }
        float psum[4] = {0, 0, 0, 0};
        for (int ct = 0; ct < 4; ++ct)
            for (int r = 0; r < 4; ++r) {
                float e = __expf(p[ct][r] - rm[r]);  // masked -> exp(-inf) = 0
                p[ct][r] = e;
                psum[r] += e;
            }
        for (int m = 1; m < 16; m <<= 1)
            for (int r = 0; r < 4; ++r)
                psum[r] += __shfl_xor(psum[r], m, 64);
        for (int r = 0; r < 4; ++r) rs[r] = rs[r] * fac[r] + psum[r];
        for (int d = 0; d < 4; ++d) {
            f32x4 a = acc[d];
            for (int r = 0; r < 4; ++r) a[r] *= fac[r];
            acc[d] = a;
        }

        // ---- P (bf16) to per-wave LDS, swizzled ----
        char* lpw = (char*)&lP[w][0];
        for (int ct = 0; ct < 4; ++ct)
            for (int r = 0; r < 4; ++r) {
                int rowl = g * 4 + r;
                int byteoff = (rowl * 128 + (ct * 16 + ln) * 2) ^ ((rowl & 7) << 4);
                *(unsigned short*)(lpw + byteoff) = f2bf(p[ct][r]);
            }
        __syncthreads();

        // ---- ctx += P V ----
        for (int d = 0; d < 4; ++d) {
            for (int kc = 0; kc < 2; ++kc) {
                int pboff = (ln * 128 + kc * 64 + g * 16) ^ ((ln & 7) << 4);
                bf16x8 ap = *(const bf16x8*)(lpw + pboff);
                int vrow2 = d * 16 + ln;
                int vboff = (vrow2 * 128 + kc * 64 + g * 16) ^ ((vrow2 & 7) << 4);
                bf16x8 bv = *(const bf16x8*)((const char*)lVT + vboff);
                acc[d] = __builtin_amdgcn_mfma_f32_16x16x32_bf16(ap, bv, acc[d], 0, 0, 0);
            }
        }
        __syncthreads();
    }

    // ---- write ctx (bf16), layout [s][h*64+d] ----
    for (int d = 0; d < 4; ++d)
        for (int r = 0; r < 4; ++r) {
            int rowg = q0 + g * 4 + r;
            int colg = h * 64 + d * 16 + ln;
            ctxb[(size_t)rowg * D_MODEL + colg] = f2bf(acc[d][r] / rs[r]);
        }
}

// ---------------- host side ----------------
extern "C" void kernel_launch(void* const* d_in, const int* in_sizes, int n_in,
                              void* d_out, int out_size, void* d_ws, size_t ws_size,
                              hipStream_t stream) {
    const float* x  = (const float*)d_in[0];
    const float* Wq = (const float*)d_in[1];
    const float* Wk = (const float*)d_in[2];
    const float* Wv = (const float*)d_in[3];
    const float* Wo = (const float*)d_in[4];
    const int* tpos = (const int*)d_in[5];
    float* out = (float*)d_out;

    char* ws = (char*)d_ws;
    unsigned short* xb   = (unsigned short*)(ws + 0);
    unsigned short* Wqb  = (unsigned short*)(ws + 8388608);
    unsigned short* Wkb  = (unsigned short*)(ws + 10485760);
    unsigned short* Wvb  = (unsigned short*)(ws + 12582912);
    unsigned short* Wob  = (unsigned short*)(ws + 14680064);
    unsigned short* Qbuf = (unsigned short*)(ws + 16777216);
    unsigned short* Kbuf = (unsigned short*)(ws + 25165824);
    unsigned short* Vbuf = (unsigned short*)(ws + 33554432);
    unsigned short* ctxb = (unsigned short*)(ws + 41943040);
    float* costab = (float*)(ws + 50331648);
    float* sintab = (float*)(ws + 50855936);

    to_bf16_k<<<4096, 256, 0, stream>>>(x, xb, S_LEN * D_MODEL);
    to_bf16_k<<<1024, 256, 0, stream>>>(Wq, Wqb, D_MODEL * D_MODEL);
    to_bf16_k<<<1024, 256, 0, stream>>>(Wk, Wkb, D_MODEL * D_MODEL);
    to_bf16_k<<<1024, 256, 0, stream>>>(Wv, Wvb, D_MODEL * D_MODEL);
    to_bf16_k<<<1024, 256, 0, stream>>>(Wo, Wob, D_MODEL * D_MODEL);
    rope_tables_k<<<512, 256, 0, stream>>>(tpos, costab, sintab);

    dim3 gg(D_MODEL / 128, S_LEN / 128);   // (8, 32)
    gemm_nt_k<1><<<gg, 256, 0, stream>>>(xb, Wqb, Qbuf, S_LEN, D_MODEL, D_MODEL, costab, sintab);
    gemm_nt_k<1><<<gg, 256, 0, stream>>>(xb, Wkb, Kbuf, S_LEN, D_MODEL, D_MODEL, costab, sintab);
    gemm_nt_k<0><<<gg, 256, 0, stream>>>(xb, Wvb, Vbuf, S_LEN, D_MODEL, D_MODEL, nullptr, nullptr);

    attn_k<<<dim3(N_HEADS, S_LEN / 64), 256, 0, stream>>>(Qbuf, Kbuf, Vbuf, ctxb);

    gemm_nt_k<2><<<gg, 256, 0, stream>>>(ctxb, Wob, out, S_LEN, D_MODEL, D_MODEL, nullptr, nullptr);
}